// Round 1
// baseline (41.166 us; speedup 1.0000x reference)
//
#include <hip/hip_runtime.h>
#include <math.h>

#define BATCH 16
#define LSEQ 768
#define NCHUNK 12
#define CHUNK 64

// ---------- geometry helpers (match reference arithmetic) ----------

__device__ inline void angle_sc(const float c[][3], int i, float& s, float& co) {
    float v1x = c[i][0]-c[i+1][0], v1y = c[i][1]-c[i+1][1], v1z = c[i][2]-c[i+1][2];
    float v2x = c[i+2][0]-c[i+1][0], v2y = c[i+2][1]-c[i+1][1], v2z = c[i+2][2]-c[i+1][2];
    float dot = v1x*v2x + v1y*v2y + v1z*v2z;
    float n1 = sqrtf(v1x*v1x + v1y*v1y + v1z*v1z);
    float n2 = sqrtf(v2x*v2x + v2y*v2y + v2z*v2z);
    float cv = dot / (n1*n2 + 1e-6f);
    cv = fminf(1.f, fmaxf(-1.f, cv));
    co = cv;
    s  = sqrtf(fmaxf(0.f, 1.f - cv*cv));   // sin(arccos(cv))
}

__device__ inline void dih_sc(const float c[][3], int i, float& s, float& co) {
    float v1x = c[i+1][0]-c[i][0],   v1y = c[i+1][1]-c[i][1],   v1z = c[i+1][2]-c[i][2];
    float v2x = c[i+2][0]-c[i+1][0], v2y = c[i+2][1]-c[i+1][1], v2z = c[i+2][2]-c[i+1][2];
    float v3x = c[i+3][0]-c[i+2][0], v3y = c[i+3][1]-c[i+2][1], v3z = c[i+3][2]-c[i+2][2];
    float n1x = v1y*v2z - v1z*v2y, n1y = v1z*v2x - v1x*v2z, n1z = v1x*v2y - v1y*v2x;
    float n2x = v2y*v3z - v2z*v3y, n2y = v2z*v3x - v2x*v3z, n2z = v2x*v3y - v2y*v3x;
    float dot = n1x*n2x + n1y*n2y + n1z*n2z;
    float l1 = sqrtf(n1x*n1x + n1y*n1y + n1z*n1z);
    float l2 = sqrtf(n2x*n2x + n2y*n2y + n2z*n2z);
    float cv = dot / (l1*l2 + 1e-6f);
    cv = fminf(1.f, fmaxf(-1.f, cv));
    float sinp = sqrtf(fmaxf(0.f, 1.f - cv*cv));
    // sign(dot(cross(n1,n2), v2))
    float cx = n1y*n2z - n1z*n2y, cy = n1z*n2x - n1x*n2z, cz = n1x*n2y - n1y*n2x;
    float sg = cx*v2x + cy*v2y + cz*v2z;
    float sgn = (sg > 0.f) ? 1.f : ((sg < 0.f) ? -1.f : 0.f);
    co = cv;
    s  = sgn * sinp;   // sin(sign*phi); cos(sign*phi)=cos(phi)
}

// ---------- kernel 1: stable compaction + angle/torsion sums ----------

__global__ __launch_bounds__(256) void k_compact(
    const float* __restrict__ pred, const float* __restrict__ targ,
    const int* __restrict__ gm,
    float4* __restrict__ predc, float4* __restrict__ targc,
    int* __restrict__ counts, float* __restrict__ asum, float* __restrict__ tsum)
{
    const int b = blockIdx.x;
    const int t = threadIdx.x;
    __shared__ float cp[LSEQ][3];
    __shared__ float ctg[LSEQ][3];
    __shared__ int   scan[256];
    __shared__ float red[256];

    // zero compacted arrays (padding must be exact zeros, like the reference)
    for (int i = t; i < LSEQ*3; i += 256) { ((float*)cp)[i] = 0.f; ((float*)ctg)[i] = 0.f; }

    const int i0 = 3*t;
    const int* gmb = gm + b*LSEQ;
    const int m0 = gmb[i0], m1 = gmb[i0+1], m2 = gmb[i0+2];
    const int lsum = m0 + m1 + m2;
    scan[t] = lsum;
    __syncthreads();
    // Hillis-Steele inclusive scan over 256 thread sums
    for (int off = 1; off < 256; off <<= 1) {
        int v = scan[t];
        int add = (t >= off) ? scan[t-off] : 0;
        __syncthreads();
        scan[t] = v + add;
        __syncthreads();
    }
    const int n = scan[255];
    int d = scan[t] - lsum;   // exclusive prefix

    const float* pb = pred + b*LSEQ*3;
    const float* tb = targ + b*LSEQ*3;
    if (m0) { int i = i0;
        cp[d][0]=pb[3*i+0]; cp[d][1]=pb[3*i+1]; cp[d][2]=pb[3*i+2];
        ctg[d][0]=tb[3*i+0]; ctg[d][1]=tb[3*i+1]; ctg[d][2]=tb[3*i+2]; d++; }
    if (m1) { int i = i0+1;
        cp[d][0]=pb[3*i+0]; cp[d][1]=pb[3*i+1]; cp[d][2]=pb[3*i+2];
        ctg[d][0]=tb[3*i+0]; ctg[d][1]=tb[3*i+1]; ctg[d][2]=tb[3*i+2]; d++; }
    if (m2) { int i = i0+2;
        cp[d][0]=pb[3*i+0]; cp[d][1]=pb[3*i+1]; cp[d][2]=pb[3*i+2];
        ctg[d][0]=tb[3*i+0]; ctg[d][1]=tb[3*i+1]; ctg[d][2]=tb[3*i+2]; d++; }
    __syncthreads();

    // write compacted coords + squared norms to global ws
    for (int j = t; j < LSEQ; j += 256) {
        float x = cp[j][0],  y = cp[j][1],  z = cp[j][2];
        predc[b*LSEQ + j] = make_float4(x, y, z, x*x + y*y + z*z);
        x = ctg[j][0]; y = ctg[j][1]; z = ctg[j][2];
        targc[b*LSEQ + j] = make_float4(x, y, z, x*x + y*y + z*z);
    }
    if (t == 0) counts[b] = n;

    // angle (i in [0,765], incl. iff i+1<n) and torsion (i in [0,764], incl. iff i+2<n)
    float a_acc = 0.f, t_acc = 0.f;
    for (int i = t; i < LSEQ-2; i += 256) {
        if (i + 1 < n) {
            float sp, cpv, st, ctv;
            angle_sc(cp, i, sp, cpv);
            angle_sc(ctg, i, st, ctv);
            float ds = sp - st, dc = cpv - ctv;
            a_acc += ds*ds + dc*dc;
        }
        if (i < LSEQ-3 && i + 2 < n) {
            float sp, cpv, st, ctv;
            dih_sc(cp, i, sp, cpv);
            dih_sc(ctg, i, st, ctv);
            float ds = sp - st, dc = cpv - ctv;
            t_acc += ds*ds + dc*dc;
        }
    }
    red[t] = a_acc; __syncthreads();
    for (int off = 128; off > 0; off >>= 1) { if (t < off) red[t] += red[t+off]; __syncthreads(); }
    if (t == 0) asum[b] = red[0];
    __syncthreads();
    red[t] = t_acc; __syncthreads();
    for (int off = 128; off > 0; off >>= 1) { if (t < off) red[t] += red[t+off]; __syncthreads(); }
    if (t == 0) tsum[b] = red[0];
}

// ---------- kernel 2: pairwise dist + clash partials ----------

__global__ __launch_bounds__(256) void k_pair(
    const float4* __restrict__ predc, const float4* __restrict__ targc,
    const int* __restrict__ counts, float2* __restrict__ parts)
{
    const int b = blockIdx.y;
    const int c = blockIdx.x;
    const int t = threadIdx.x;
    __shared__ float4 sp[LSEQ];
    __shared__ float4 st[LSEQ];
    __shared__ float red[256];

    const int n  = counts[b];
    const int r0 = c * CHUNK;
    float dist = 0.f, clash = 0.f;

    if (r0 < n) {
        for (int j = t; j < LSEQ; j += 256) { sp[j] = predc[b*LSEQ+j]; st[j] = targc[b*LSEQ+j]; }
        __syncthreads();
        const int r1 = min(r0 + CHUNK, n);
        for (int r = r0; r < r1; ++r) {
            const float4 ai = sp[r];
            const float4 bi = st[r];
            for (int j = t; j < n; j += 256) {
                float4 aj = sp[j];
                float4 bj = st[j];
                float sq1 = fmaxf(ai.w + aj.w - 2.f*(ai.x*aj.x + ai.y*aj.y + ai.z*aj.z), 1e-12f);
                float d1  = sqrtf(sq1);
                float sq2 = fmaxf(bi.w + bj.w - 2.f*(bi.x*bj.x + bi.y*bj.y + bi.z*bj.z), 1e-12f);
                float d2  = sqrtf(sq2);
                float dd = d1 - d2;
                dist += dd*dd;
                if (d1 < 3.8f && d1 > 2.0f) { float cv = 3.8f - d1; clash += cv*cv; }
            }
        }
    }
    red[t] = dist; __syncthreads();
    for (int off = 128; off > 0; off >>= 1) { if (t < off) red[t] += red[t+off]; __syncthreads(); }
    float dtot = red[0];
    __syncthreads();
    red[t] = clash; __syncthreads();
    for (int off = 128; off > 0; off >>= 1) { if (t < off) red[t] += red[t+off]; __syncthreads(); }
    if (t == 0) parts[b*NCHUNK + c] = make_float2(dtot, red[0]);
}

// ---------- kernel 3: final per-batch normalization + mean ----------

__global__ __launch_bounds__(64) void k_final(
    const int* __restrict__ counts, const float* __restrict__ asum,
    const float* __restrict__ tsum, const float2* __restrict__ parts,
    float* __restrict__ out)
{
    const int t = threadIdx.x;
    float angle = 0.f, tors = 0.f, dist = 0.f, clash = 0.f;
    if (t < BATCH) {
        const int n = counts[t];
        float dsum = 0.f, csum = 0.f;
        for (int c = 0; c < NCHUNK; ++c) { float2 p = parts[t*NCHUNK + c]; dsum += p.x; csum += p.y; }
        float denom = (float)(n*n) + 1e-8f;
        dist  = dsum / denom;
        clash = csum / denom;
        int ca = n - 1; if (ca < 0) ca = 0; if (ca > LSEQ-2) ca = LSEQ-2;
        int ct = n - 2; if (ct < 0) ct = 0; if (ct > LSEQ-3) ct = LSEQ-3;
        angle = asum[t] / fmaxf((float)ca, 1e-6f);
        tors  = tsum[t] / fmaxf((float)ct, 1e-6f);
    }
    // wave-level sum over 64 lanes (only lanes 0..15 carry values)
    for (int off = 32; off > 0; off >>= 1) {
        angle += __shfl_down(angle, off);
        tors  += __shfl_down(tors,  off);
        dist  += __shfl_down(dist,  off);
        clash += __shfl_down(clash, off);
    }
    if (t == 0) {
        out[0] = angle / (float)BATCH;
        out[1] = tors  / (float)BATCH;
        out[2] = dist  / (float)BATCH;
        out[3] = dist  / (float)BATCH;   // inter_dist_loss aliases dist_loss
        out[4] = clash / (float)BATCH;
    }
}

extern "C" void kernel_launch(void* const* d_in, const int* in_sizes, int n_in,
                              void* d_out, int out_size, void* d_ws, size_t ws_size,
                              hipStream_t stream) {
    (void)in_sizes; (void)n_in; (void)out_size; (void)ws_size;
    const float* pred = (const float*)d_in[0];
    const float* targ = (const float*)d_in[1];
    const int*   gm   = (const int*)d_in[2];
    // d_in[3] (poc) and d_in[4] (poc_mask) are dead in the reference.

    float4* predc  = (float4*)d_ws;
    float4* targc  = predc + BATCH*LSEQ;
    int*    counts = (int*)(targc + BATCH*LSEQ);
    float*  asum   = (float*)(counts + BATCH);
    float*  tsum   = asum + BATCH;
    float2* parts  = (float2*)(tsum + BATCH);
    float*  out    = (float*)d_out;

    k_compact<<<BATCH, 256, 0, stream>>>(pred, targ, gm, predc, targc, counts, asum, tsum);
    k_pair<<<dim3(NCHUNK, BATCH), 256, 0, stream>>>(predc, targc, counts, parts);
    k_final<<<1, 64, 0, stream>>>(counts, asum, tsum, parts, out);
}

// Round 2
// 19.026 us; speedup vs baseline: 2.1636x; 2.1636x over previous
//
#include <hip/hip_runtime.h>
#include <math.h>

#define BATCH 16
#define LSEQ 768
#define NCHUNK 16   // chunks per batch; grid = NCHUNK*BATCH = 256 blocks = 1 per CU

// ---------- geometry helpers on compacted float4 LDS arrays ----------
// sincos(arccos(x)) = [sqrt(1-x^2), x]  -> no trig needed.

__device__ inline void angle_sc4(const float4* __restrict__ c, int i, float& s, float& co) {
    float4 a = c[i], b = c[i+1], d = c[i+2];
    float v1x = a.x-b.x, v1y = a.y-b.y, v1z = a.z-b.z;
    float v2x = d.x-b.x, v2y = d.y-b.y, v2z = d.z-b.z;
    float dot = v1x*v2x + v1y*v2y + v1z*v2z;
    float n1 = sqrtf(v1x*v1x + v1y*v1y + v1z*v1z);
    float n2 = sqrtf(v2x*v2x + v2y*v2y + v2z*v2z);
    float cv = dot / (n1*n2 + 1e-6f);
    cv = fminf(1.f, fmaxf(-1.f, cv));
    co = cv;
    s  = sqrtf(fmaxf(0.f, 1.f - cv*cv));
}

__device__ inline void dih_sc4(const float4* __restrict__ c, int i, float& s, float& co) {
    float4 p0 = c[i], p1 = c[i+1], p2 = c[i+2], p3 = c[i+3];
    float v1x = p1.x-p0.x, v1y = p1.y-p0.y, v1z = p1.z-p0.z;
    float v2x = p2.x-p1.x, v2y = p2.y-p1.y, v2z = p2.z-p1.z;
    float v3x = p3.x-p2.x, v3y = p3.y-p2.y, v3z = p3.z-p2.z;
    float n1x = v1y*v2z - v1z*v2y, n1y = v1z*v2x - v1x*v2z, n1z = v1x*v2y - v1y*v2x;
    float n2x = v2y*v3z - v2z*v3y, n2y = v2z*v3x - v2x*v3z, n2z = v2x*v3y - v2y*v3x;
    float dot = n1x*n2x + n1y*n2y + n1z*n2z;
    float l1 = sqrtf(n1x*n1x + n1y*n1y + n1z*n1z);
    float l2 = sqrtf(n2x*n2x + n2y*n2y + n2z*n2z);
    float cv = dot / (l1*l2 + 1e-6f);
    cv = fminf(1.f, fmaxf(-1.f, cv));
    float sinp = sqrtf(fmaxf(0.f, 1.f - cv*cv));
    float cx = n1y*n2z - n1z*n2y, cy = n1z*n2x - n1x*n2z, cz = n1x*n2y - n1y*n2x;
    float sg = cx*v2x + cy*v2y + cz*v2z;
    float sgn = (sg > 0.f) ? 1.f : ((sg < 0.f) ? -1.f : 0.f);
    co = cv;
    s  = sgn * sinp;
}

// ---------- fused kernel: per-block compaction + symmetric pairwise ----------
// Block (c, b): batch b, rows r = c, c+NCHUNK, ... (interleaved -> balanced
// triangle). Pairwise sum over i<j doubled (matrix symmetric, diagonal = 0).
// Block c == NCHUNK-1 additionally computes angle/torsion sums.

__global__ __launch_bounds__(256) void k_main(
    const float* __restrict__ pred, const float* __restrict__ targ,
    const int* __restrict__ gm,
    float2* __restrict__ parts, float* __restrict__ an, float* __restrict__ tn)
{
    const int b = blockIdx.y;
    const int c = blockIdx.x;
    const int t = threadIdx.x;
    const int lane = t & 63;
    const int wid = t >> 6;

    __shared__ float4 sp[LSEQ];   // compacted pred (xyz + |.|^2)
    __shared__ float4 st[LSEQ];   // compacted target
    __shared__ int   wtot[4];
    __shared__ float wred[4][2];

    // --- mask load + wave-shuffle scan (stable partition offsets) ---
    const int* gmb = gm + b*LSEQ;
    const int i0 = 3*t;
    const int m0 = gmb[i0], m1 = gmb[i0+1], m2 = gmb[i0+2];
    const int lsum = m0 + m1 + m2;
    int inc = lsum;
    #pragma unroll
    for (int off = 1; off < 64; off <<= 1) {
        int v = __shfl_up(inc, off);
        if (lane >= off) inc += v;
    }
    if (lane == 63) wtot[wid] = inc;
    __syncthreads();
    int woff = 0;
    #pragma unroll
    for (int w = 0; w < 4; ++w) if (w < wid) woff += wtot[w];
    const int n = wtot[0] + wtot[1] + wtot[2] + wtot[3];
    int d = woff + inc - lsum;   // exclusive prefix = destination slot

    // zero only the padding tail [n, LSEQ) (disjoint from scatter [0,n))
    for (int j = n + t; j < LSEQ; j += 256) {
        sp[j] = make_float4(0.f, 0.f, 0.f, 0.f);
        st[j] = make_float4(0.f, 0.f, 0.f, 0.f);
    }
    const float* pb = pred + b*LSEQ*3;
    const float* tb = targ + b*LSEQ*3;
    #define SCAT(mm, ii) if (mm) { \
        float x = pb[3*(ii)], y = pb[3*(ii)+1], z = pb[3*(ii)+2]; \
        sp[d] = make_float4(x, y, z, x*x + y*y + z*z); \
        x = tb[3*(ii)]; y = tb[3*(ii)+1]; z = tb[3*(ii)+2]; \
        st[d] = make_float4(x, y, z, x*x + y*y + z*z); \
        d++; }
    SCAT(m0, i0) SCAT(m1, i0+1) SCAT(m2, i0+2)
    #undef SCAT
    __syncthreads();

    // --- pairwise dist + clash over upper triangle (doubled) ---
    float dist = 0.f, clash = 0.f;
    for (int r = c; r < n; r += NCHUNK) {
        const float4 ai = sp[r];
        const float4 bi = st[r];
        for (int j = r + 1 + t; j < n; j += 256) {
            float4 aj = sp[j];
            float4 bj = st[j];
            float sq1 = fmaxf(ai.w + aj.w - 2.f*(ai.x*aj.x + ai.y*aj.y + ai.z*aj.z), 1e-12f);
            float d1  = sqrtf(sq1);
            float sq2 = fmaxf(bi.w + bj.w - 2.f*(bi.x*bj.x + bi.y*bj.y + bi.z*bj.z), 1e-12f);
            float d2  = sqrtf(sq2);
            float dd = d1 - d2;
            dist += dd*dd;
            if (d1 < 3.8f && d1 > 2.0f) { float cv = 3.8f - d1; clash += cv*cv; }
        }
    }
    #pragma unroll
    for (int off = 32; off; off >>= 1) {
        dist  += __shfl_down(dist,  off);
        clash += __shfl_down(clash, off);
    }
    if (lane == 0) { wred[wid][0] = dist; wred[wid][1] = clash; }
    __syncthreads();
    if (t == 0) {
        float ds = wred[0][0] + wred[1][0] + wred[2][0] + wred[3][0];
        float cs = wred[0][1] + wred[1][1] + wred[2][1] + wred[3][1];
        float denom = (float)n * (float)n + 1e-8f;
        parts[b*NCHUNK + c] = make_float2(2.f*ds/denom, 2.f*cs/denom);
    }

    // --- angle + torsion (one chunk per batch does it; LDS already compacted) ---
    if (c == NCHUNK-1) {
        float aacc = 0.f, tacc = 0.f;
        for (int i = t; i < LSEQ-2; i += 256) {
            if (i + 1 < n) {
                float s1, c1, s2, c2;
                angle_sc4(sp, i, s1, c1);
                angle_sc4(st, i, s2, c2);
                float ds = s1 - s2, dc = c1 - c2;
                aacc += ds*ds + dc*dc;
            }
            if (i < LSEQ-3 && i + 2 < n) {
                float s1, c1, s2, c2;
                dih_sc4(sp, i, s1, c1);
                dih_sc4(st, i, s2, c2);
                float ds = s1 - s2, dc = c1 - c2;
                tacc += ds*ds + dc*dc;
            }
        }
        #pragma unroll
        for (int off = 32; off; off >>= 1) {
            aacc += __shfl_down(aacc, off);
            tacc += __shfl_down(tacc, off);
        }
        __syncthreads();   // wred reuse
        if (lane == 0) { wred[wid][0] = aacc; wred[wid][1] = tacc; }
        __syncthreads();
        if (t == 0) {
            float as = wred[0][0] + wred[1][0] + wred[2][0] + wred[3][0];
            float ts = wred[0][1] + wred[1][1] + wred[2][1] + wred[3][1];
            int cai = n - 1; if (cai < 0) cai = 0; if (cai > LSEQ-2) cai = LSEQ-2;
            int cti = n - 2; if (cti < 0) cti = 0; if (cti > LSEQ-3) cti = LSEQ-3;
            an[b] = as / fmaxf((float)cai, 1e-6f);
            tn[b] = ts / fmaxf((float)cti, 1e-6f);
        }
    }
}

// ---------- final deterministic reduce (1 block) ----------

__global__ __launch_bounds__(256) void k_final(
    const float2* __restrict__ parts, const float* __restrict__ an,
    const float* __restrict__ tn, float* __restrict__ out)
{
    const int t = threadIdx.x;
    const int lane = t & 63;
    const int wid = t >> 6;
    __shared__ float wred[4][4];

    float2 p = parts[t];           // exactly NCHUNK*BATCH = 256 entries
    float dist = p.x, clash = p.y;
    float a  = (t < BATCH) ? an[t] : 0.f;
    float to = (t < BATCH) ? tn[t] : 0.f;
    #pragma unroll
    for (int off = 32; off; off >>= 1) {
        dist  += __shfl_down(dist,  off);
        clash += __shfl_down(clash, off);
        a     += __shfl_down(a,     off);
        to    += __shfl_down(to,    off);
    }
    if (lane == 0) { wred[wid][0]=dist; wred[wid][1]=clash; wred[wid][2]=a; wred[wid][3]=to; }
    __syncthreads();
    if (t == 0) {
        float d = 0.f, cl = 0.f, aa = 0.f, tt = 0.f;
        #pragma unroll
        for (int w = 0; w < 4; ++w) { d += wred[w][0]; cl += wred[w][1]; aa += wred[w][2]; tt += wred[w][3]; }
        out[0] = aa / (float)BATCH;
        out[1] = tt / (float)BATCH;
        out[2] = d  / (float)BATCH;
        out[3] = d  / (float)BATCH;   // inter_dist_loss aliases dist_loss
        out[4] = cl / (float)BATCH;
    }
}

extern "C" void kernel_launch(void* const* d_in, const int* in_sizes, int n_in,
                              void* d_out, int out_size, void* d_ws, size_t ws_size,
                              hipStream_t stream) {
    (void)in_sizes; (void)n_in; (void)out_size; (void)ws_size;
    const float* pred = (const float*)d_in[0];
    const float* targ = (const float*)d_in[1];
    const int*   gm   = (const int*)d_in[2];
    // d_in[3] (poc) and d_in[4] (poc_mask) are dead in the reference.

    float2* parts = (float2*)d_ws;                 // NCHUNK*BATCH entries
    float*  an    = (float*)(parts + NCHUNK*BATCH);
    float*  tn    = an + BATCH;
    float*  out   = (float*)d_out;

    k_main<<<dim3(NCHUNK, BATCH), 256, 0, stream>>>(pred, targ, gm, parts, an, tn);
    k_final<<<1, 256, 0, stream>>>(parts, an, tn, out);
}